// Round 1
// baseline (988.336 us; speedup 1.0000x reference)
//
#include <hip/hip_runtime.h>

// Problem constants
#define BB   256
#define PP   196
#define ED   2048
#define AD   512
#define MROWS (BB * PP)          // 50176
#define AWE_ELEMS (BB * ED)      // 524288 (output 0)
#define ALPHA_ELEMS (BB * PP)    // 50176  (output 1)

typedef __bf16 bf16x8 __attribute__((ext_vector_type(8)));
typedef float  f32x4  __attribute__((ext_vector_type(4)));

__device__ __forceinline__ f32x4 mfma16(bf16x8 a, bf16x8 b, f32x4 c) {
    return __builtin_amdgcn_mfma_f32_16x16x32_bf16(a, b, c, 0, 0, 0);
}

__device__ __forceinline__ bf16x8 pack8(float4 a, float4 b) {
    bf16x8 r;
    r[0] = (__bf16)a.x; r[1] = (__bf16)a.y; r[2] = (__bf16)a.z; r[3] = (__bf16)a.w;
    r[4] = (__bf16)b.x; r[5] = (__bf16)b.y; r[6] = (__bf16)b.z; r[7] = (__bf16)b.w;
    return r;
}

// ---------------- prep kernels ----------------

// zero att accumulator (50176 floats = 12544 float4 = 49 * 256)
__global__ void zero_att_k(float4* __restrict__ att4) {
    att4[blockIdx.x * 256 + threadIdx.x] = make_float4(0.f, 0.f, 0.f, 0.f);
}

// WeT[n][k] = bf16(We[k][n]); WeT is 512 x 2048
__global__ void wet_k(const float* __restrict__ We, unsigned short* __restrict__ WeT) {
    int idx = blockIdx.x * 256 + threadIdx.x;     // 0 .. 1048575
    int n = idx >> 11;
    int k = idx & 2047;
    __bf16 h = (__bf16)We[k * AD + n];
    WeT[idx] = __builtin_bit_cast(unsigned short, h);
}

// att2p[b][a] = sum_d dh[b,d] * Wd[d,a] + Wd_b[a] + We_b[a]
__global__ void att2_k(const float* __restrict__ dh, const float* __restrict__ Wd,
                       const float* __restrict__ Wd_b, const float* __restrict__ We_b,
                       float* __restrict__ att2p) {
    int b = blockIdx.x;
    int t = threadIdx.x;  // 256
    __shared__ float dhs[512];
    dhs[t]       = dh[b * 512 + t];
    dhs[t + 256] = dh[b * 512 + 256 + t];
    __syncthreads();
    float a0 = 0.f, a1 = 0.f;
    #pragma unroll 4
    for (int d = 0; d < 512; d++) {
        float x = dhs[d];
        a0 = fmaf(x, Wd[d * AD + t], a0);
        a1 = fmaf(x, Wd[d * AD + 256 + t], a1);
    }
    att2p[b * AD + t]       = a0 + Wd_b[t]       + We_b[t];
    att2p[b * AD + 256 + t] = a1 + Wd_b[t + 256] + We_b[t + 256];
}

// ---------------- main GEMM + relu + Wf-dot ----------------
// tile: 128 rows x 128 cols (n-chunk) x BK=64, 4 waves in 2x2 quadrants of 64x64
__global__ __launch_bounds__(256) void gemm_att(
    const float* __restrict__ enc, const unsigned short* __restrict__ WeT,
    const float* __restrict__ att2p, const float* __restrict__ Wf,
    float* __restrict__ att)
{
    __shared__ alignas(16) unsigned short As[128 * 64];  // [m][k] bf16
    __shared__ alignas(16) unsigned short Bs[128 * 64];  // [n][k] bf16

    const int tid  = threadIdx.x;
    const int wave = tid >> 6;
    const int lane = tid & 63;
    const int lr   = lane & 15;
    const int quad = lane >> 4;
    const int rq = (wave & 1) * 64;   // row quadrant base
    const int cq = (wave >> 1) * 64;  // col quadrant base
    const int row_base = blockIdx.x * 128;
    const int n_base   = blockIdx.y * 128;

    f32x4 acc[4][4];
    #pragma unroll
    for (int i = 0; i < 4; i++)
        #pragma unroll
        for (int j = 0; j < 4; j++)
            acc[i][j] = (f32x4){0.f, 0.f, 0.f, 0.f};

    // A staging: thread t covers row t>>1, k-span (t&1)*32 .. +32
    const int arow  = tid >> 1;
    const int akoff = (tid & 1) * 32;
    const float* aptr = enc + (size_t)(row_base + arow) * ED + akoff;
    bf16x8* awr = (bf16x8*)&As[arow * 64 + akoff];

    // B staging (async, from WeT[n][k] bf16): wave handles chunks wave*4 .. +3
    const unsigned short* bsrc = WeT + (size_t)n_base * ED;

    for (int kb = 0; kb < ED; kb += 64) {
        // async global->LDS for B
        #pragma unroll
        for (int i = 0; i < 4; i++) {
            int c = wave * 4 + i;                      // chunk 0..15, 8 n-rows each
            int n = c * 8 + (lane >> 3);
            const unsigned short* src = bsrc + (size_t)n * ED + kb + (lane & 7) * 8;
            unsigned short* dst = &Bs[c * 512];
            __builtin_amdgcn_global_load_lds(
                (const __attribute__((address_space(1))) void*)src,
                (__attribute__((address_space(3))) void*)dst, 16, 0, 0);
        }
        // A: 8 float4 loads, convert, 4 x b128 LDS writes
        const float4* ap = (const float4*)(aptr + kb);
        float4 f0 = ap[0], f1 = ap[1], f2 = ap[2], f3 = ap[3];
        float4 f4 = ap[4], f5 = ap[5], f6 = ap[6], f7 = ap[7];
        awr[0] = pack8(f0, f1);
        awr[1] = pack8(f2, f3);
        awr[2] = pack8(f4, f5);
        awr[3] = pack8(f6, f7);

        __syncthreads();

        #pragma unroll
        for (int ks = 0; ks < 2; ks++) {
            bf16x8 af[4], bfr[4];
            #pragma unroll
            for (int i = 0; i < 4; i++)
                af[i] = *(const bf16x8*)&As[(rq + i * 16 + lr) * 64 + ks * 32 + quad * 8];
            #pragma unroll
            for (int j = 0; j < 4; j++)
                bfr[j] = *(const bf16x8*)&Bs[(cq + j * 16 + lr) * 64 + ks * 32 + quad * 8];
            #pragma unroll
            for (int i = 0; i < 4; i++)
                #pragma unroll
                for (int j = 0; j < 4; j++)
                    acc[i][j] = mfma16(af[i], bfr[j], acc[i][j]);
        }
        __syncthreads();
    }

    // epilogue: h = relu(acc + bias); partial att row-sum = sum_cols h*Wf ; atomicAdd
    float wf[4];
    int colg[4];
    #pragma unroll
    for (int j = 0; j < 4; j++) {
        colg[j] = n_base + cq + j * 16 + lr;
        wf[j] = Wf[colg[j]];
    }
    #pragma unroll
    for (int i = 0; i < 4; i++) {
        int row0 = row_base + rq + i * 16 + quad * 4;
        #pragma unroll
        for (int r = 0; r < 4; r++) {
            int row = row0 + r;
            unsigned bidx = (unsigned)row / 196u;
            const float* bias = att2p + bidx * AD;
            float s = 0.f;
            #pragma unroll
            for (int j = 0; j < 4; j++) {
                float v = acc[i][j][r] + bias[colg[j]];
                v = fmaxf(v, 0.f);
                s = fmaf(v, wf[j], s);
            }
            s += __shfl_xor(s, 1);
            s += __shfl_xor(s, 2);
            s += __shfl_xor(s, 4);
            s += __shfl_xor(s, 8);
            if (lr == 0) atomicAdd(&att[row], s);
        }
    }
}

// ---------------- softmax over P per b ----------------
__global__ void softmax_k(const float* __restrict__ att, float* __restrict__ alpha) {
    int b = blockIdx.x;
    int l = threadIdx.x;  // 64
    float v[4];
    float m = -1e30f;
    #pragma unroll
    for (int i = 0; i < 4; i++) {
        int p = l + i * 64;
        v[i] = (p < PP) ? att[b * PP + p] : -1e30f;
        m = fmaxf(m, v[i]);
    }
    #pragma unroll
    for (int off = 32; off > 0; off >>= 1) m = fmaxf(m, __shfl_xor(m, off));
    float s = 0.f;
    #pragma unroll
    for (int i = 0; i < 4; i++) {
        int p = l + i * 64;
        v[i] = (p < PP) ? __expf(v[i] - m) : 0.f;
        s += v[i];
    }
    #pragma unroll
    for (int off = 32; off > 0; off >>= 1) s += __shfl_xor(s, off);
    float inv = 1.0f / s;
    #pragma unroll
    for (int i = 0; i < 4; i++) {
        int p = l + i * 64;
        if (p < PP) alpha[b * PP + p] = v[i] * inv;
    }
}

// ---------------- awe = sum_p alpha[b,p] * enc[b,p,:] ----------------
__global__ __launch_bounds__(256) void awe_k(const float* __restrict__ enc,
                                             const float* __restrict__ alpha,
                                             float* __restrict__ awe) {
    int b = blockIdx.x;
    int ec = blockIdx.y;      // 0..1, 1024-float chunk of E
    int t = threadIdx.x;      // 256
    __shared__ float al[PP];
    if (t < PP) al[t] = alpha[b * PP + t];
    __syncthreads();

    const float4* bp = (const float4*)enc + ((size_t)b * PP * (ED / 4) + ec * 256 + t);
    float4 acc = make_float4(0.f, 0.f, 0.f, 0.f);
    #pragma unroll 4
    for (int p = 0; p < PP; p++) {
        float a = al[p];
        float4 x = bp[(size_t)p * (ED / 4)];
        acc.x = fmaf(a, x.x, acc.x);
        acc.y = fmaf(a, x.y, acc.y);
        acc.z = fmaf(a, x.z, acc.z);
        acc.w = fmaf(a, x.w, acc.w);
    }
    float4* ow = (float4*)awe + ((size_t)b * (ED / 4) + ec * 256 + t);
    *ow = acc;
}

// ---------------- launch ----------------
extern "C" void kernel_launch(void* const* d_in, const int* in_sizes, int n_in,
                              void* d_out, int out_size, void* d_ws, size_t ws_size,
                              hipStream_t stream) {
    const float* enc  = (const float*)d_in[0];  // (256,196,2048)
    const float* dh   = (const float*)d_in[1];  // (1,256,512)
    const float* We   = (const float*)d_in[2];  // (2048,512)
    const float* We_b = (const float*)d_in[3];  // (512,)
    const float* Wd   = (const float*)d_in[4];  // (512,512)
    const float* Wd_b = (const float*)d_in[5];  // (512,)
    const float* Wf   = (const float*)d_in[6];  // (512,)
    // Wf_b (d_in[7]) cancels in softmax — unused.

    float* out = (float*)d_out;                 // [awe (524288) | alpha (50176)]

    // workspace layout
    float*          att   = (float*)d_ws;                              // 50176 f32
    unsigned short* WeT   = (unsigned short*)((char*)d_ws + 262144);   // 512x2048 bf16 (2 MB)
    float*          att2p = (float*)((char*)d_ws + 262144 + 2097152);  // 256x512 f32

    zero_att_k<<<49, 256, 0, stream>>>((float4*)att);
    wet_k<<<4096, 256, 0, stream>>>(We, WeT);
    att2_k<<<256, 256, 0, stream>>>(dh, Wd, Wd_b, We_b, att2p);
    gemm_att<<<dim3(392, 4), 256, 0, stream>>>(enc, WeT, att2p, Wf, att);
    softmax_k<<<256, 64, 0, stream>>>(att, out + AWE_ELEMS);
    awe_k<<<dim3(256, 2), 256, 0, stream>>>(enc, out + AWE_ELEMS, out);
}

// Round 2
// 858.978 us; speedup vs baseline: 1.1506x; 1.1506x over previous
//
#include <hip/hip_runtime.h>

// Problem constants
#define BB   256
#define PP   196
#define ED   2048
#define AD   512
#define AWE_ELEMS (BB * ED)      // 524288 (output 0)

typedef __bf16 bf16x8 __attribute__((ext_vector_type(8)));
typedef float  f32x4  __attribute__((ext_vector_type(4)));

__device__ __forceinline__ f32x4 mfma16(bf16x8 a, bf16x8 b, f32x4 c) {
    return __builtin_amdgcn_mfma_f32_16x16x32_bf16(a, b, c, 0, 0, 0);
}

__device__ __forceinline__ bf16x8 pack8(float4 a, float4 b) {
    bf16x8 r;
    r[0] = (__bf16)a.x; r[1] = (__bf16)a.y; r[2] = (__bf16)a.z; r[3] = (__bf16)a.w;
    r[4] = (__bf16)b.x; r[5] = (__bf16)b.y; r[6] = (__bf16)b.z; r[7] = (__bf16)b.w;
    return r;
}

__device__ __forceinline__ unsigned short bfbits(float x) {
    return __builtin_bit_cast(unsigned short, (__bf16)x);
}

// ---------------- prep kernels ----------------

// zero att accumulator (50176 floats = 12544 float4 = 49 * 256)
__global__ void zero_att_k(float4* __restrict__ att4) {
    att4[blockIdx.x * 256 + threadIdx.x] = make_float4(0.f, 0.f, 0.f, 0.f);
}

// WeT[n][k] = bf16(We[k][n]) via 64x64 LDS-tiled transpose.
// grid (32, 8): blockIdx.x = k-tile, blockIdx.y = n-tile; 256 threads.
__global__ void wet_k(const float* __restrict__ We, unsigned short* __restrict__ WeT) {
    __shared__ unsigned short S[64][72];   // [n][k], padded row (+8 shorts)
    const int t  = threadIdx.x;
    const int k0 = blockIdx.x * 64;
    const int n0 = blockIdx.y * 64;

    const int rr = t >> 4;    // 0..15 (k row within group)
    const int c4 = t & 15;    // float4 column
    #pragma unroll
    for (int i = 0; i < 4; i++) {
        int kr = i * 16 + rr;
        float4 v = *(const float4*)&We[(size_t)(k0 + kr) * AD + n0 + c4 * 4];
        S[c4 * 4 + 0][kr] = bfbits(v.x);
        S[c4 * 4 + 1][kr] = bfbits(v.y);
        S[c4 * 4 + 2][kr] = bfbits(v.z);
        S[c4 * 4 + 3][kr] = bfbits(v.w);
    }
    __syncthreads();

    const int n = t >> 2;     // 0..63
    #pragma unroll
    for (int c = 0; c < 2; c++) {
        int ch = (t & 3) * 2 + c;   // 16B chunk of the 64-k row
        *(uint4*)&WeT[(size_t)(n0 + n) * ED + k0 + ch * 8] = *(const uint4*)&S[n][ch * 8];
    }
}

// att2p[b][a] = sum_d dh[b,d] * Wd[d,a] + Wd_b[a] + We_b[a]
__global__ void att2_k(const float* __restrict__ dh, const float* __restrict__ Wd,
                       const float* __restrict__ Wd_b, const float* __restrict__ We_b,
                       float* __restrict__ att2p) {
    int b = blockIdx.x;
    int t = threadIdx.x;  // 256
    __shared__ float dhs[512];
    dhs[t]       = dh[b * 512 + t];
    dhs[t + 256] = dh[b * 512 + 256 + t];
    __syncthreads();
    float a0 = 0.f, a1 = 0.f;
    #pragma unroll 4
    for (int d = 0; d < 512; d++) {
        float x = dhs[d];
        a0 = fmaf(x, Wd[d * AD + t], a0);
        a1 = fmaf(x, Wd[d * AD + 256 + t], a1);
    }
    att2p[b * AD + t]       = a0 + Wd_b[t]       + We_b[t];
    att2p[b * AD + 256 + t] = a1 + Wd_b[t + 256] + We_b[t + 256];
}

// ---------------- main GEMM + relu + Wf-dot ----------------
// tile: 128 rows x 128 cols x BK=64, 4 waves in 2x2 quadrants of 64x64.
// LDS XOR-swizzle: element (row, logical 16B-chunk c) stored at physical
// chunk c ^ (row & 7) -> fragment reads spread over all 8 bank groups.
__global__ __launch_bounds__(256) void gemm_att(
    const float* __restrict__ enc, const unsigned short* __restrict__ WeT,
    const float* __restrict__ att2p, const float* __restrict__ Wf,
    float* __restrict__ att)
{
    __shared__ alignas(16) unsigned short As[128 * 64];  // [m][k] bf16, swizzled
    __shared__ alignas(16) unsigned short Bs[128 * 64];  // [n][k] bf16, swizzled

    const int tid  = threadIdx.x;
    const int wave = tid >> 6;
    const int lane = tid & 63;
    const int lr   = lane & 15;
    const int quad = lane >> 4;
    const int swz  = lr & 7;
    const int rq = (wave & 1) * 64;   // row quadrant base
    const int cq = (wave >> 1) * 64;  // col quadrant base

    // XCD-aware decode: 4 n-tiles of one row-tile land on the same XCD in
    // adjacent dispatch slots -> A re-reads hit that XCD's L2.
    const int id  = blockIdx.x;        // 0..1567
    const int xcd = id & 7;
    const int t2  = id >> 3;           // 0..195
    const int ny  = t2 & 3;
    const int rg  = t2 >> 2;           // 0..48
    const int row_base = (rg * 8 + xcd) * 128;
    const int n_base   = ny * 128;

    f32x4 acc[4][4];
    #pragma unroll
    for (int i = 0; i < 4; i++)
        #pragma unroll
        for (int j = 0; j < 4; j++)
            acc[i][j] = (f32x4){0.f, 0.f, 0.f, 0.f};

    // A staging: thread t covers row t>>1, logical chunks (t&1)*4 .. +3
    const int arow  = tid >> 1;
    const int akoff = (tid & 1) * 32;               // float offset
    const float* aptr = enc + (size_t)(row_base + arow) * ED + akoff;
    const int asw = arow & 7;

    // B staging (async): lane covers n = c*8 + (lane>>3); source chunk is
    // swizzled so the lane-contiguous LDS image is the swizzled layout.
    const unsigned short* bsrc = WeT + (size_t)n_base * ED;
    const int bn  = lane >> 3;
    const int bjj = (lane & 7) ^ bn;                // source 16B chunk

    for (int kb = 0; kb < ED; kb += 64) {
        // async global->LDS for B (swizzled source gather, coalesced per 8 lanes)
        #pragma unroll
        for (int i = 0; i < 4; i++) {
            int c = wave * 4 + i;                   // chunk 0..15, 8 n-rows each
            const unsigned short* src = bsrc + (size_t)(c * 8 + bn) * ED + kb + bjj * 8;
            unsigned short* dst = &Bs[c * 512];
            __builtin_amdgcn_global_load_lds(
                (const __attribute__((address_space(1))) void*)src,
                (__attribute__((address_space(3))) void*)dst, 16, 0, 0);
        }
        // A: 8 float4 loads, convert, 4 swizzled b128 LDS writes
        const float4* ap = (const float4*)(aptr + kb);
        float4 f0 = ap[0], f1 = ap[1], f2 = ap[2], f3 = ap[3];
        float4 f4 = ap[4], f5 = ap[5], f6 = ap[6], f7 = ap[7];
        {
            int lc0 = (tid & 1) * 4;
            *(bf16x8*)&As[arow * 64 + ((lc0 + 0) ^ asw) * 8] = pack8(f0, f1);
            *(bf16x8*)&As[arow * 64 + ((lc0 + 1) ^ asw) * 8] = pack8(f2, f3);
            *(bf16x8*)&As[arow * 64 + ((lc0 + 2) ^ asw) * 8] = pack8(f4, f5);
            *(bf16x8*)&As[arow * 64 + ((lc0 + 3) ^ asw) * 8] = pack8(f6, f7);
        }

        __syncthreads();

        #pragma unroll
        for (int ks = 0; ks < 2; ks++) {
            bf16x8 af[4], bfr[4];
            int pc = ((ks * 4 + quad) ^ swz) * 8;   // physical chunk offset (shorts)
            #pragma unroll
            for (int i = 0; i < 4; i++)
                af[i] = *(const bf16x8*)&As[(rq + i * 16 + lr) * 64 + pc];
            #pragma unroll
            for (int j = 0; j < 4; j++)
                bfr[j] = *(const bf16x8*)&Bs[(cq + j * 16 + lr) * 64 + pc];
            #pragma unroll
            for (int i = 0; i < 4; i++)
                #pragma unroll
                for (int j = 0; j < 4; j++)
                    acc[i][j] = mfma16(af[i], bfr[j], acc[i][j]);
        }
        __syncthreads();
    }

    // epilogue: h = relu(acc + bias); partial att row-sum = sum_cols h*Wf ; atomicAdd
    float wf[4];
    int colg[4];
    #pragma unroll
    for (int j = 0; j < 4; j++) {
        colg[j] = n_base + cq + j * 16 + lr;
        wf[j] = Wf[colg[j]];
    }
    #pragma unroll
    for (int i = 0; i < 4; i++) {
        int row0 = row_base + rq + i * 16 + quad * 4;
        #pragma unroll
        for (int r = 0; r < 4; r++) {
            int row = row0 + r;
            unsigned bidx = (unsigned)row / 196u;
            const float* bias = att2p + bidx * AD;
            float s = 0.f;
            #pragma unroll
            for (int j = 0; j < 4; j++) {
                float v = acc[i][j][r] + bias[colg[j]];
                v = fmaxf(v, 0.f);
                s = fmaf(v, wf[j], s);
            }
            s += __shfl_xor(s, 1);
            s += __shfl_xor(s, 2);
            s += __shfl_xor(s, 4);
            s += __shfl_xor(s, 8);
            if (lr == 0) atomicAdd(&att[row], s);
        }
    }
}

// ---------------- softmax over P per b ----------------
__global__ void softmax_k(const float* __restrict__ att, float* __restrict__ alpha) {
    int b = blockIdx.x;
    int l = threadIdx.x;  // 64
    float v[4];
    float m = -1e30f;
    #pragma unroll
    for (int i = 0; i < 4; i++) {
        int p = l + i * 64;
        v[i] = (p < PP) ? att[b * PP + p] : -1e30f;
        m = fmaxf(m, v[i]);
    }
    #pragma unroll
    for (int off = 32; off > 0; off >>= 1) m = fmaxf(m, __shfl_xor(m, off));
    float s = 0.f;
    #pragma unroll
    for (int i = 0; i < 4; i++) {
        int p = l + i * 64;
        v[i] = (p < PP) ? __expf(v[i] - m) : 0.f;
        s += v[i];
    }
    #pragma unroll
    for (int off = 32; off > 0; off >>= 1) s += __shfl_xor(s, off);
    float inv = 1.0f / s;
    #pragma unroll
    for (int i = 0; i < 4; i++) {
        int p = l + i * 64;
        if (p < PP) alpha[b * PP + p] = v[i] * inv;
    }
}

// ---------------- awe = sum_p alpha[b,p] * enc[b,p,:] ----------------
__global__ __launch_bounds__(256) void awe_k(const float* __restrict__ enc,
                                             const float* __restrict__ alpha,
                                             float* __restrict__ awe) {
    int b = blockIdx.x;
    int ec = blockIdx.y;      // 0..1, 1024-float chunk of E
    int t = threadIdx.x;      // 256
    __shared__ float al[PP];
    if (t < PP) al[t] = alpha[b * PP + t];
    __syncthreads();

    const float4* bp = (const float4*)enc + ((size_t)b * PP * (ED / 4) + ec * 256 + t);
    float4 acc = make_float4(0.f, 0.f, 0.f, 0.f);
    #pragma unroll 4
    for (int p = 0; p < PP; p++) {
        float a = al[p];
        float4 x = bp[(size_t)p * (ED / 4)];
        acc.x = fmaf(a, x.x, acc.x);
        acc.y = fmaf(a, x.y, acc.y);
        acc.z = fmaf(a, x.z, acc.z);
        acc.w = fmaf(a, x.w, acc.w);
    }
    float4* ow = (float4*)awe + ((size_t)b * (ED / 4) + ec * 256 + t);
    *ow = acc;
}

// ---------------- launch ----------------
extern "C" void kernel_launch(void* const* d_in, const int* in_sizes, int n_in,
                              void* d_out, int out_size, void* d_ws, size_t ws_size,
                              hipStream_t stream) {
    const float* enc  = (const float*)d_in[0];  // (256,196,2048)
    const float* dh   = (const float*)d_in[1];  // (1,256,512)
    const float* We   = (const float*)d_in[2];  // (2048,512)
    const float* We_b = (const float*)d_in[3];  // (512,)
    const float* Wd   = (const float*)d_in[4];  // (512,512)
    const float* Wd_b = (const float*)d_in[5];  // (512,)
    const float* Wf   = (const float*)d_in[6];  // (512,)
    // Wf_b (d_in[7]) cancels in softmax — unused.

    float* out = (float*)d_out;                 // [awe (524288) | alpha (50176)]

    // workspace layout
    float*          att   = (float*)d_ws;                              // 50176 f32
    unsigned short* WeT   = (unsigned short*)((char*)d_ws + 262144);   // 512x2048 bf16 (2 MB)
    float*          att2p = (float*)((char*)d_ws + 262144 + 2097152);  // 256x512 f32

    zero_att_k<<<49, 256, 0, stream>>>((float4*)att);
    wet_k<<<dim3(32, 8), 256, 0, stream>>>(We, WeT);
    att2_k<<<256, 256, 0, stream>>>(dh, Wd, Wd_b, We_b, att2p);
    gemm_att<<<1568, 256, 0, stream>>>(enc, WeT, att2p, Wf, att);
    softmax_k<<<256, 64, 0, stream>>>(att, out + AWE_ELEMS);
    awe_k<<<dim3(256, 2), 256, 0, stream>>>(enc, out + AWE_ELEMS, out);
}